// Round 2
// baseline (7736.214 us; speedup 1.0000x reference)
//
#include <hip/hip_runtime.h>
#include <hip/hip_bf16.h>
#include <stdint.h>
#include <math.h>

// ---------------------------------------------------------------------------
// PCN Exploration layer. B=4, S=1024, D=1024, NS=8, NT=10.
// Closed form: hyp = a*(hidden + 0.1*expl) + (1-a)*cp + sum_j c_j * noise_j
//   a = 0.99^10, c_j = 0.01*0.99^(10-j), j=1..9 (noise key = fold_in(key42, j))
// PRNG: JAX threefry2x32. PARTITIONABLE=1 -> bits[i] = w0^w1 of cipher(key,(0,i))
// Workspace-light design (~213 KB of d_ws): hyp/Y never materialized in HBM.
//   - k_fused_energy: per-block 32-row panel; hyp gen -> GEMM1(+ce) -> LN ->
//     relu -> GEMM2 -> relu -> dot Ew3 -> erows. Panels in LDS (bf16).
//   - k_select: recompute hyp noise (bit-identical threefry) + softmax mix.
// ---------------------------------------------------------------------------

#define PARTITIONABLE 1

#define NS_ 8
#define B_ 4
#define S_ 1024
#define D_ 1024
#define NROWS (NS_*B_*S_)          // 32768
#define NELEM (NS_*B_*S_*D_)       // 2^25

struct RngParams {
  uint32_t k0[10];
  uint32_t k1[10];
  float coef[10];   // coef[0]=0.1*a (expl), coef[j]=0.01*0.99^(10-j)
  float aH;         // 0.99^10
  float aCP;        // 1 - 0.99^10
};

// ----------------------------- threefry -----------------------------------
__host__ __device__ __forceinline__ uint32_t rotl32_(uint32_t x, int r) {
  return (x << r) | (x >> (32 - r));
}

__host__ __device__ __forceinline__ void tf2x32(uint32_t k0, uint32_t k1,
                                                uint32_t x0, uint32_t x1,
                                                uint32_t &o0, uint32_t &o1) {
  uint32_t k2 = k0 ^ k1 ^ 0x1BD11BDAu;
  x0 += k0; x1 += k1;
  x0 += x1; x1 = rotl32_(x1, 13); x1 ^= x0;
  x0 += x1; x1 = rotl32_(x1, 15); x1 ^= x0;
  x0 += x1; x1 = rotl32_(x1, 26); x1 ^= x0;
  x0 += x1; x1 = rotl32_(x1, 6);  x1 ^= x0;
  x0 += k1; x1 += k2 + 1u;
  x0 += x1; x1 = rotl32_(x1, 17); x1 ^= x0;
  x0 += x1; x1 = rotl32_(x1, 29); x1 ^= x0;
  x0 += x1; x1 = rotl32_(x1, 16); x1 ^= x0;
  x0 += x1; x1 = rotl32_(x1, 24); x1 ^= x0;
  x0 += k2; x1 += k0 + 2u;
  x0 += x1; x1 = rotl32_(x1, 13); x1 ^= x0;
  x0 += x1; x1 = rotl32_(x1, 15); x1 ^= x0;
  x0 += x1; x1 = rotl32_(x1, 26); x1 ^= x0;
  x0 += x1; x1 = rotl32_(x1, 6);  x1 ^= x0;
  x0 += k0; x1 += k1 + 3u;
  x0 += x1; x1 = rotl32_(x1, 17); x1 ^= x0;
  x0 += x1; x1 = rotl32_(x1, 29); x1 ^= x0;
  x0 += x1; x1 = rotl32_(x1, 16); x1 ^= x0;
  x0 += x1; x1 = rotl32_(x1, 24); x1 ^= x0;
  x0 += k1; x1 += k2 + 4u;
  x0 += x1; x1 = rotl32_(x1, 13); x1 ^= x0;
  x0 += x1; x1 = rotl32_(x1, 15); x1 ^= x0;
  x0 += x1; x1 = rotl32_(x1, 26); x1 ^= x0;
  x0 += x1; x1 = rotl32_(x1, 6);  x1 ^= x0;
  x0 += k2; x1 += k0 + 5u;
  o0 = x0; o1 = x1;
}

// bits -> N(0,1) matching jax.random.normal f32 (XLA ErfInv32 polynomial)
__device__ __forceinline__ float bits_to_normal(uint32_t bits) {
  const float lo = -0.99999994f;
  float f = __uint_as_float((bits >> 9) | 0x3f800000u) - 1.0f;
  float x = fmaxf(lo, f * 2.0f + lo);
  float w = -log1pf(-x * x);
  float p;
  if (w < 5.0f) {
    w = w - 2.5f;
    p = 2.81022636e-08f;
    p = fmaf(p, w, 3.43273939e-07f);
    p = fmaf(p, w, -3.5233877e-06f);
    p = fmaf(p, w, -4.39150654e-06f);
    p = fmaf(p, w, 0.00021858087f);
    p = fmaf(p, w, -0.00125372503f);
    p = fmaf(p, w, -0.00417768164f);
    p = fmaf(p, w, 0.246640727f);
    p = fmaf(p, w, 1.50140941f);
  } else {
    w = sqrtf(w) - 3.0f;
    p = -0.000200214257f;
    p = fmaf(p, w, 0.000100950558f);
    p = fmaf(p, w, 0.00134934322f);
    p = fmaf(p, w, -0.00367342844f);
    p = fmaf(p, w, 0.00573950773f);
    p = fmaf(p, w, -0.0076224613f);
    p = fmaf(p, w, 0.00943887047f);
    p = fmaf(p, w, 1.00167406f);
    p = fmaf(p, w, 2.83297682f);
  }
  return 1.41421356f * (p * x);
}

// weighted 10-stream noise for flat element index i
__device__ __forceinline__ float noise10(const RngParams& P, uint32_t i) {
  float acc = 0.f;
  #pragma unroll
  for (int j = 0; j < 10; ++j) {
    uint32_t w0, w1;
#if PARTITIONABLE
    tf2x32(P.k0[j], P.k1[j], 0u, i, w0, w1);
    acc = fmaf(P.coef[j], bits_to_normal(w0 ^ w1), acc);
#else
    const uint32_t H = 1u << 24;
    uint32_t lo = (i < H) ? i : (i - H);
    tf2x32(P.k0[j], P.k1[j], lo, lo + H, w0, w1);
    acc = fmaf(P.coef[j], bits_to_normal((i < H) ? w0 : w1), acc);
#endif
  }
  return acc;
}

// ----------------------------- small kernels -------------------------------
// ctx[b][d] = mean_s hidden[b][s][d]
__global__ void k_ctx(const float* __restrict__ hidden, float* __restrict__ ctx) {
  int idx = blockIdx.x * 256 + threadIdx.x;      // 0..4095
  int b = idx >> 10, d = idx & 1023;
  const float* p = hidden + (size_t)b * (S_ * D_) + d;
  float s = 0.f;
  #pragma unroll 8
  for (int t = 0; t < S_; ++t) s += p[(size_t)t << 10];
  ctx[idx] = s * (1.0f / 1024.0f);
}

// t1[b][j] = ctx[b] . W1[:,j] + b1[j]   (j in [0,2048))
__global__ void k_fc1(const float* __restrict__ ctx, const float* __restrict__ W1,
                      const float* __restrict__ b1, float* __restrict__ t1) {
  int idx = blockIdx.x * 256 + threadIdx.x;      // 0..8191
  int b = idx >> 11, j = idx & 2047;
  const float* c = ctx + b * 1024;
  const float* w = W1 + j;
  float s = 0.f;
  #pragma unroll 8
  for (int k = 0; k < 1024; ++k) s += c[k] * w[(size_t)k * 2048];
  t1[idx] = s + b1[j];
}

// in-place LN + relu on rows of t1 (4 rows x 2048)
__global__ void k_ln_relu(float* __restrict__ t1, const float* __restrict__ g,
                          const float* __restrict__ bb) {
  __shared__ float red[256];
  int row = blockIdx.x, tid = threadIdx.x;
  float* x = t1 + row * 2048;
  float v[8];
  #pragma unroll
  for (int q = 0; q < 8; ++q) v[q] = x[tid + q * 256];
  float s = 0.f;
  #pragma unroll
  for (int q = 0; q < 8; ++q) s += v[q];
  red[tid] = s; __syncthreads();
  for (int off = 128; off > 0; off >>= 1) { if (tid < off) red[tid] += red[tid + off]; __syncthreads(); }
  float m = red[0] * (1.0f / 2048.0f);
  __syncthreads();
  float s2 = 0.f;
  #pragma unroll
  for (int q = 0; q < 8; ++q) { float d = v[q] - m; s2 += d * d; }
  red[tid] = s2; __syncthreads();
  for (int off = 128; off > 0; off >>= 1) { if (tid < off) red[tid] += red[tid + off]; __syncthreads(); }
  float var = red[0] * (1.0f / 2048.0f);
  float rs = 1.0f / sqrtf(var + 1e-5f);
  #pragma unroll
  for (int q = 0; q < 8; ++q) {
    int j = tid + q * 256;
    float z = (v[q] - m) * rs * g[j] + bb[j];
    x[j] = fmaxf(z, 0.0f);
  }
}

// y==0: cp[b][j] = t1n[b] . W2[:,j] + b2[j]   (K=2048)
// y==1: ce[b][j] = ctx[b] . Ew1c[:,j] + Eb1[j] (K=1024)
__global__ void k_fc2(const float* __restrict__ t1, const float* __restrict__ W2,
                      const float* __restrict__ b2, const float* __restrict__ ctx,
                      const float* __restrict__ Ew1c, const float* __restrict__ Eb1,
                      float* __restrict__ cp, float* __restrict__ ce) {
  int idx = blockIdx.x * 256 + threadIdx.x;      // 0..4095
  int b = idx >> 10, j = idx & 1023;
  if (blockIdx.y == 0) {
    const float* a = t1 + b * 2048;
    const float* w = W2 + j;
    float s = 0.f;
    #pragma unroll 8
    for (int k = 0; k < 2048; ++k) s += a[k] * w[(size_t)k * 1024];
    cp[idx] = s + b2[j];
  } else {
    const float* a = ctx + b * 1024;
    const float* w = Ew1c + j;
    float s = 0.f;
    #pragma unroll 8
    for (int k = 0; k < 1024; ++k) s += a[k] * w[(size_t)k * 1024];
    ce[idx] = s + Eb1[j];
  }
}

// ----------------------------- fused energy --------------------------------
// One block = 32 rows of the (32768 x 1024) hyp matrix (same n,b per block).
// LDS: Apan (hyp, bf16 64KB), Zpan (Y then Z, bf16 64KB), Wst (8KB), misc.
__global__ __launch_bounds__(256, 1) void k_fused_energy(
    const float* __restrict__ hidden, const float* __restrict__ cp,
    const float* __restrict__ ce, const float* __restrict__ Ew1,
    const float* __restrict__ Eln_g, const float* __restrict__ Eln_b,
    const float* __restrict__ Ew2, const float* __restrict__ Eb2,
    const float* __restrict__ Ew3, float* __restrict__ erows, RngParams P)
{
  __shared__ __hip_bfloat16 Apan[32][1024];   // 64 KB
  __shared__ __hip_bfloat16 Zpan[32][1024];   // 64 KB
  __shared__ float Wst[16][128];              // 8 KB
  __shared__ float red[32][16];               // 2 KB
  __shared__ float rowm[32], rowr[32];

  const int tid = threadIdx.x;
  const int r0 = blockIdx.x * 32;
  const int bidx = (r0 >> 10) & 3;            // batch index (const per block)

  // ---- phase 1: generate hyp panel into Apan (bf16) ----
  for (int q = 0; q < 128; ++q) {
    int e = tid + q * 256;
    int row = e >> 10, col = e & 1023;
    uint32_t i = (uint32_t)(r0 + row) * 1024u + (uint32_t)col;
    float nz = noise10(P, i);
    uint32_t bsd = i & 0x3FFFFFu;
    float v = fmaf(P.aH, hidden[bsd], fmaf(P.aCP, cp[(bidx << 10) | col], nz));
    Apan[row][col] = __float2bfloat16(v);
  }
  __syncthreads();

  const int tx = tid & 15, ty = tid >> 4;
  const int row0t = ty * 2;                   // thread's 2 rows
  const int tc0 = tx * 8;                     // thread's 8 cols in tile
  const int kr = tid >> 4;                    // staging row 0..15
  const int kc = (tid & 15) * 8;              // staging col offset

  // ---- phase 2: Y = Apan @ Ew1h + ce, store bf16 into Zpan ----
  for (int tile = 0; tile < 8; ++tile) {
    int ct0 = tile * 128;
    float acc[2][8] = {};
    for (int kt = 0; kt < 1024; kt += 16) {
      __syncthreads();
      const float* src = Ew1 + (size_t)(kt + kr) * 1024 + ct0 + kc;
      *(float4*)&Wst[kr][kc]     = *(const float4*)(src);
      *(float4*)&Wst[kr][kc + 4] = *(const float4*)(src + 4);
      __syncthreads();
      #pragma unroll
      for (int kk = 0; kk < 16; ++kk) {
        float a0 = __bfloat162float(Apan[row0t][kt + kk]);
        float a1 = __bfloat162float(Apan[row0t + 1][kt + kk]);
        #pragma unroll
        for (int j = 0; j < 8; ++j) {
          float w = Wst[kk][tc0 + j];
          acc[0][j] = fmaf(a0, w, acc[0][j]);
          acc[1][j] = fmaf(a1, w, acc[1][j]);
        }
      }
    }
    #pragma unroll
    for (int i2 = 0; i2 < 2; ++i2)
      #pragma unroll
      for (int j = 0; j < 8; ++j) {
        int c = ct0 + tc0 + j;
        Zpan[row0t + i2][c] = __float2bfloat16(acc[i2][j] + ce[(bidx << 10) + c]);
      }
  }
  __syncthreads();

  // ---- phase 3: LN row stats (8 lanes per row, contiguous in wave) ----
  {
    int row = tid >> 3, l8 = tid & 7;
    float s1 = 0.f, s2 = 0.f;
    for (int j = 0; j < 128; ++j) {
      float v = __bfloat162float(Zpan[row][l8 + j * 8]);
      s1 += v; s2 = fmaf(v, v, s2);
    }
    #pragma unroll
    for (int o = 4; o > 0; o >>= 1) {
      s1 += __shfl_down(s1, o, 8);
      s2 += __shfl_down(s2, o, 8);
    }
    if (l8 == 0) {
      float m = s1 * (1.0f / 1024.0f);
      float var = fmaxf(s2 * (1.0f / 1024.0f) - m * m, 0.0f);
      rowm[row] = m;
      rowr[row] = 1.0f / sqrtf(var + 1e-5f);
    }
  }
  __syncthreads();

  // ---- phase 4: Z = relu(LN(Y)) in place ----
  for (int q = 0; q < 128; ++q) {
    int e = tid + q * 256;
    int row = e >> 10, col = e & 1023;
    float v = __bfloat162float(Zpan[row][col]);
    float z = (v - rowm[row]) * rowr[row] * Eln_g[col] + Eln_b[col];
    Zpan[row][col] = __float2bfloat16(fmaxf(z, 0.f));
  }
  __syncthreads();

  // ---- phase 5: U = relu(Zpan @ Ew2 + Eb2); e-partial = U . Ew3 ----
  float ep[2] = {0.f, 0.f};
  for (int tile = 0; tile < 4; ++tile) {
    int ct0 = tile * 128;
    float acc[2][8] = {};
    for (int kt = 0; kt < 1024; kt += 16) {
      __syncthreads();
      const float* src = Ew2 + (size_t)(kt + kr) * 512 + ct0 + kc;
      *(float4*)&Wst[kr][kc]     = *(const float4*)(src);
      *(float4*)&Wst[kr][kc + 4] = *(const float4*)(src + 4);
      __syncthreads();
      #pragma unroll
      for (int kk = 0; kk < 16; ++kk) {
        float a0 = __bfloat162float(Zpan[row0t][kt + kk]);
        float a1 = __bfloat162float(Zpan[row0t + 1][kt + kk]);
        #pragma unroll
        for (int j = 0; j < 8; ++j) {
          float w = Wst[kk][tc0 + j];
          acc[0][j] = fmaf(a0, w, acc[0][j]);
          acc[1][j] = fmaf(a1, w, acc[1][j]);
        }
      }
    }
    #pragma unroll
    for (int i2 = 0; i2 < 2; ++i2)
      #pragma unroll
      for (int j = 0; j < 8; ++j) {
        int c = ct0 + tc0 + j;
        float u = fmaxf(acc[i2][j] + Eb2[c], 0.f);
        ep[i2] = fmaf(u, Ew3[c], ep[i2]);
      }
  }
  red[row0t][tx]     = ep[0];
  red[row0t + 1][tx] = ep[1];
  __syncthreads();
  if (tid < 32) {
    float s = 0.f;
    #pragma unroll
    for (int t = 0; t < 16; ++t) s += red[tid][t];
    erows[r0 + tid] = s;                      // exclusive write, no atomics
  }
}

// energies[nb] = mean_s erows + Eb3
__global__ void k_energy(const float* __restrict__ erows, const float* __restrict__ Eb3,
                         float* __restrict__ energ) {
  __shared__ float red[256];
  int nb = blockIdx.x, tid = threadIdx.x;
  const float* x = erows + nb * 1024;
  float s = x[tid] + x[tid + 256] + x[tid + 512] + x[tid + 768];
  red[tid] = s; __syncthreads();
  for (int off = 128; off > 0; off >>= 1) { if (tid < off) red[tid] += red[tid + off]; __syncthreads(); }
  if (tid == 0) energ[nb] = red[0] * (1.0f / 1024.0f) + Eb3[0];
}

// out[b,s,d] = base + sum_n softmax_n(-E)[n,b] * noise_n   (hyp recomputed)
__global__ __launch_bounds__(256) void k_select(
    const float* __restrict__ hidden, const float* __restrict__ cp,
    const float* __restrict__ energ, float* __restrict__ out, RngParams P)
{
  uint32_t idx = blockIdx.x * 256u + threadIdx.x;   // 0..2^22-1 (b,s,d)
  uint32_t b = (idx >> 20) & 3u;
  uint32_t d = idx & 1023u;
  float e[8];
  #pragma unroll
  for (int n = 0; n < 8; ++n) e[n] = -energ[n * 4 + b];
  float mx = e[0];
  #pragma unroll
  for (int n = 1; n < 8; ++n) mx = fmaxf(mx, e[n]);
  float p[8]; float s = 0.f;
  #pragma unroll
  for (int n = 0; n < 8; ++n) { p[n] = expf(e[n] - mx); s += p[n]; }
  float inv = 1.0f / s;
  float base = fmaf(P.aH, hidden[idx], P.aCP * cp[(b << 10) | d]);
  float acc = 0.f;
  #pragma unroll
  for (int n = 0; n < 8; ++n)
    acc = fmaf(p[n], noise10(P, idx + ((uint32_t)n << 22)), acc);
  out[idx] = base + acc * inv;
}

// ---------------------------------------------------------------------------
extern "C" void kernel_launch(void* const* d_in, const int* in_sizes, int n_in,
                              void* d_out, int out_size, void* d_ws, size_t ws_size,
                              hipStream_t stream) {
  const float* hidden = (const float*)d_in[0];
  const float* W1    = (const float*)d_in[1];
  const float* b1    = (const float*)d_in[2];
  const float* ln1_g = (const float*)d_in[3];
  const float* ln1_b = (const float*)d_in[4];
  const float* W2    = (const float*)d_in[5];
  const float* b2    = (const float*)d_in[6];
  const float* Ew1   = (const float*)d_in[7];
  const float* Eb1   = (const float*)d_in[8];
  const float* Eln_g = (const float*)d_in[9];
  const float* Eln_b = (const float*)d_in[10];
  const float* Ew2   = (const float*)d_in[11];
  const float* Eb2   = (const float*)d_in[12];
  const float* Ew3   = (const float*)d_in[13];
  const float* Eb3   = (const float*)d_in[14];
  float* out = (float*)d_out;

  // workspace: ~213 KB total
  float* ctx   = (float*)d_ws;        // 4096
  float* t1    = ctx + 4096;          // 8192
  float* cp    = t1 + 8192;           // 4096
  float* ce    = cp + 4096;           // 4096
  float* erows = ce + 4096;           // 32768
  float* energ = erows + 32768;       // 32

  // host-side: fold-in keys K_t = threefry((0,42),(0,t)), t=0..9, and coeffs
  RngParams P;
  for (uint32_t t = 0; t < 10; ++t) {
    uint32_t o0, o1;
    tf2x32(0u, 42u, 0u, t, o0, o1);
    P.k0[t] = o0; P.k1[t] = o1;
  }
  double a = pow(0.99, 10);
  P.coef[0] = (float)(0.1 * a);
  for (int j = 1; j <= 9; ++j) P.coef[j] = (float)(0.01 * pow(0.99, 10 - j));
  P.aH = (float)a;
  P.aCP = (float)(1.0 - a);

  k_ctx<<<16, 256, 0, stream>>>(hidden, ctx);
  k_fc1<<<32, 256, 0, stream>>>(ctx, W1, b1, t1);
  k_ln_relu<<<4, 256, 0, stream>>>(t1, ln1_g, ln1_b);
  k_fc2<<<dim3(16, 2), 256, 0, stream>>>(t1, W2, b2, ctx, Ew1 + (size_t)1024 * 1024, Eb1, cp, ce);
  k_fused_energy<<<1024, 256, 0, stream>>>(hidden, cp, ce, Ew1, Eln_g, Eln_b,
                                           Ew2, Eb2, Ew3, erows, P);
  k_energy<<<32, 256, 0, stream>>>(erows, Eb3, energ);
  k_select<<<NELEM / 8 / 256, 256, 0, stream>>>(hidden, cp, energ, out, P);
}

// Round 3
// 1319.899 us; speedup vs baseline: 5.8612x; 5.8612x over previous
//
#include <hip/hip_runtime.h>
#include <hip/hip_bf16.h>
#include <stdint.h>
#include <math.h>

// ---------------------------------------------------------------------------
// PCN Exploration layer. B=4, S=1024, D=1024, NS=8, NT=10.
// hyp = a*(hidden + 0.1*expl) + (1-a)*cp + sum_j c_j*noise_j  (a=0.99^10)
// Round 3: MFMA bf16 GEMMs, single-pass threefry noise stored bf16 in ws,
// XOR-swizzled LDS panels. ws usage ~67.3MB (guarded; fallback recomputes).
// ---------------------------------------------------------------------------

#define NS_ 8
#define B_ 4
#define S_ 1024
#define D_ 1024
#define NROWS (NS_*B_*S_)            // 32768
#define NELEM (1u<<25)

typedef __attribute__((ext_vector_type(8))) short short8;
typedef __attribute__((ext_vector_type(4))) float f32x4;

struct RngParams {
  uint32_t k0[10], k1[10];
  float coef[10];
  float aH, aCP;
};

// ----------------------------- threefry -----------------------------------
__host__ __device__ __forceinline__ uint32_t rotl32_(uint32_t x, int r) {
  return (x << r) | (x >> (32 - r));
}

__host__ __device__ __forceinline__ void tf2x32(uint32_t k0, uint32_t k1,
                                                uint32_t x0, uint32_t x1,
                                                uint32_t &o0, uint32_t &o1) {
  uint32_t k2 = k0 ^ k1 ^ 0x1BD11BDAu;
  x0 += k0; x1 += k1;
  x0 += x1; x1 = rotl32_(x1, 13); x1 ^= x0;
  x0 += x1; x1 = rotl32_(x1, 15); x1 ^= x0;
  x0 += x1; x1 = rotl32_(x1, 26); x1 ^= x0;
  x0 += x1; x1 = rotl32_(x1, 6);  x1 ^= x0;
  x0 += k1; x1 += k2 + 1u;
  x0 += x1; x1 = rotl32_(x1, 17); x1 ^= x0;
  x0 += x1; x1 = rotl32_(x1, 29); x1 ^= x0;
  x0 += x1; x1 = rotl32_(x1, 16); x1 ^= x0;
  x0 += x1; x1 = rotl32_(x1, 24); x1 ^= x0;
  x0 += k2; x1 += k0 + 2u;
  x0 += x1; x1 = rotl32_(x1, 13); x1 ^= x0;
  x0 += x1; x1 = rotl32_(x1, 15); x1 ^= x0;
  x0 += x1; x1 = rotl32_(x1, 26); x1 ^= x0;
  x0 += x1; x1 = rotl32_(x1, 6);  x1 ^= x0;
  x0 += k0; x1 += k1 + 3u;
  x0 += x1; x1 = rotl32_(x1, 17); x1 ^= x0;
  x0 += x1; x1 = rotl32_(x1, 29); x1 ^= x0;
  x0 += x1; x1 = rotl32_(x1, 16); x1 ^= x0;
  x0 += x1; x1 = rotl32_(x1, 24); x1 ^= x0;
  x0 += k1; x1 += k2 + 4u;
  x0 += x1; x1 = rotl32_(x1, 13); x1 ^= x0;
  x0 += x1; x1 = rotl32_(x1, 15); x1 ^= x0;
  x0 += x1; x1 = rotl32_(x1, 26); x1 ^= x0;
  x0 += x1; x1 = rotl32_(x1, 6);  x1 ^= x0;
  x0 += k2; x1 += k0 + 5u;
  o0 = x0; o1 = x1;
}

// bits -> N(0,1): XLA ErfInv32 poly; fast -log(1-x^2) via (1-x)(1+x)
__device__ __forceinline__ float bits_to_normal(uint32_t bits) {
  const float lo = -0.99999994f;
  float f = __uint_as_float((bits >> 9) | 0x3f800000u) - 1.0f;
  float x = fmaxf(lo, f * 2.0f + lo);
  float t = (1.0f - x) * (1.0f + x);
  float w = -__logf(t);
  float p;
  if (w < 5.0f) {
    w = w - 2.5f;
    p = 2.81022636e-08f;
    p = fmaf(p, w, 3.43273939e-07f);
    p = fmaf(p, w, -3.5233877e-06f);
    p = fmaf(p, w, -4.39150654e-06f);
    p = fmaf(p, w, 0.00021858087f);
    p = fmaf(p, w, -0.00125372503f);
    p = fmaf(p, w, -0.00417768164f);
    p = fmaf(p, w, 0.246640727f);
    p = fmaf(p, w, 1.50140941f);
  } else {
    w = sqrtf(w) - 3.0f;
    p = -0.000200214257f;
    p = fmaf(p, w, 0.000100950558f);
    p = fmaf(p, w, 0.00134934322f);
    p = fmaf(p, w, -0.00367342844f);
    p = fmaf(p, w, 0.00573950773f);
    p = fmaf(p, w, -0.0076224613f);
    p = fmaf(p, w, 0.00943887047f);
    p = fmaf(p, w, 1.00167406f);
    p = fmaf(p, w, 2.83297682f);
  }
  return 1.41421356f * (p * x);
}

__device__ __forceinline__ float noise10(const RngParams& P, uint32_t i) {
  float acc = 0.f;
  #pragma unroll
  for (int j = 0; j < 10; ++j) {
    uint32_t w0, w1;
    tf2x32(P.k0[j], P.k1[j], 0u, i, w0, w1);
    acc = fmaf(P.coef[j], bits_to_normal(w0 ^ w1), acc);
  }
  return acc;
}

__device__ __forceinline__ uint16_t bf16u(float x) {
  __hip_bfloat16 h = __float2bfloat16(x);
  return *(uint16_t*)&h;
}
__device__ __forceinline__ float bf2f(uint32_t u) {
  return __uint_as_float(u << 16);
}

// ----------------------------- small kernels -------------------------------
__global__ void k_ctx(const float* __restrict__ hidden, float* __restrict__ ctx) {
  int idx = blockIdx.x * 256 + threadIdx.x;
  int b = idx >> 10, d = idx & 1023;
  const float* p = hidden + (size_t)b * (S_ * D_) + d;
  float s = 0.f;
  #pragma unroll 8
  for (int t = 0; t < S_; ++t) s += p[(size_t)t << 10];
  ctx[idx] = s * (1.0f / 1024.0f);
}

__global__ void k_fc1(const float* __restrict__ ctx, const float* __restrict__ W1,
                      const float* __restrict__ b1, float* __restrict__ t1) {
  int idx = blockIdx.x * 256 + threadIdx.x;
  int b = idx >> 11, j = idx & 2047;
  const float* c = ctx + b * 1024;
  const float* w = W1 + j;
  float s = 0.f;
  #pragma unroll 8
  for (int k = 0; k < 1024; ++k) s += c[k] * w[(size_t)k * 2048];
  t1[idx] = s + b1[j];
}

__global__ void k_ln_relu(float* __restrict__ t1, const float* __restrict__ g,
                          const float* __restrict__ bb) {
  __shared__ float red[256];
  int row = blockIdx.x, tid = threadIdx.x;
  float* x = t1 + row * 2048;
  float v[8];
  #pragma unroll
  for (int q = 0; q < 8; ++q) v[q] = x[tid + q * 256];
  float s = 0.f;
  #pragma unroll
  for (int q = 0; q < 8; ++q) s += v[q];
  red[tid] = s; __syncthreads();
  for (int off = 128; off > 0; off >>= 1) { if (tid < off) red[tid] += red[tid + off]; __syncthreads(); }
  float m = red[0] * (1.0f / 2048.0f);
  __syncthreads();
  float s2 = 0.f;
  #pragma unroll
  for (int q = 0; q < 8; ++q) { float d = v[q] - m; s2 += d * d; }
  red[tid] = s2; __syncthreads();
  for (int off = 128; off > 0; off >>= 1) { if (tid < off) red[tid] += red[tid + off]; __syncthreads(); }
  float var = red[0] * (1.0f / 2048.0f);
  float rs = 1.0f / sqrtf(var + 1e-5f);
  #pragma unroll
  for (int q = 0; q < 8; ++q) {
    int j = tid + q * 256;
    float z = (v[q] - m) * rs * g[j] + bb[j];
    x[j] = fmaxf(z, 0.0f);
  }
}

__global__ void k_fc2(const float* __restrict__ t1, const float* __restrict__ W2,
                      const float* __restrict__ b2, const float* __restrict__ ctx,
                      const float* __restrict__ Ew1c, const float* __restrict__ Eb1,
                      float* __restrict__ cp, float* __restrict__ ce) {
  int idx = blockIdx.x * 256 + threadIdx.x;
  int b = idx >> 10, j = idx & 1023;
  if (blockIdx.y == 0) {
    const float* a = t1 + b * 2048;
    const float* w = W2 + j;
    float s = 0.f;
    #pragma unroll 8
    for (int k = 0; k < 2048; ++k) s += a[k] * w[(size_t)k * 1024];
    cp[idx] = s + b2[j];
  } else {
    const float* a = ctx + b * 1024;
    const float* w = Ew1c + j;
    float s = 0.f;
    #pragma unroll 8
    for (int k = 0; k < 1024; ++k) s += a[k] * w[(size_t)k * 1024];
    ce[idx] = s + Eb1[j];
  }
}

// --------------- weight transpose + f32->bf16:  dst[N][K] = src[K][N] ------
__global__ void k_wcvt(const float* __restrict__ src, uint16_t* __restrict__ dst,
                       int K, int N) {
  __shared__ float tile[64][65];
  int n0 = blockIdx.x * 64, k0 = blockIdx.y * 64;
  int tid = threadIdx.x;
  #pragma unroll
  for (int i = 0; i < 16; ++i) {
    int lin = tid + i * 256;
    int tr = lin >> 6, tc = lin & 63;
    tile[tr][tc] = src[(size_t)(k0 + tr) * N + n0 + tc];
  }
  __syncthreads();
  #pragma unroll
  for (int i = 0; i < 8; ++i) {
    int lin = tid + i * 256;
    int tr = lin >> 5, tc2 = (lin & 31) * 2;
    uint32_t pk = (uint32_t)bf16u(tile[tc2][tr]) | ((uint32_t)bf16u(tile[tc2 + 1][tr]) << 16);
    *(uint32_t*)(&dst[(size_t)(n0 + tr) * K + k0 + tc2]) = pk;
  }
}

// ----------------------------- noise kernel --------------------------------
__global__ __launch_bounds__(256) void k_noise(uint32_t* __restrict__ nb32, RngParams P) {
  uint32_t p = blockIdx.x * 256u + threadIdx.x;   // pair index < 2^24
  uint32_t i0 = p * 2u;
  float n0 = noise10(P, i0);
  float n1 = noise10(P, i0 + 1u);
  nb32[p] = (uint32_t)bf16u(n0) | ((uint32_t)bf16u(n1) << 16);
}

// ----------------------------- fused energy (MFMA) -------------------------
// 2048 blocks x 256 thr; block = 16 rows. LDS: Apan 32K | Zpan 32K | Bs 16K.
#define APAN 0
#define ZPAN 32768
#define BSOF 65536

__device__ __forceinline__ int pswz(int row, int byteInRow) {   // panel swizzle
  return (row * 2048 + byteInRow) ^ ((row & 7) << 4);
}
__device__ __forceinline__ int bswz(int c, int kbyte) {         // B-stage swizzle
  return (c * 64 + kbyte) ^ ((c & 7) << 4);
}

template<bool STORED>
__global__ __launch_bounds__(256, 2) void k_fused(
    const float* __restrict__ hidden, const float* __restrict__ cp,
    const float* __restrict__ ce, const uint16_t* __restrict__ noiseBF,
    const uint16_t* __restrict__ WT1, const uint16_t* __restrict__ WT2,
    const float* __restrict__ Eln_g, const float* __restrict__ Eln_b,
    const float* __restrict__ Eb2, const float* __restrict__ Ew3,
    float* __restrict__ erows, RngParams P)
{
  __shared__ __align__(16) char smem[81920];
  const int tid = threadIdx.x;
  const int lane = tid & 63;
  const int w = tid >> 6;
  const int rl = lane & 15;
  const int kg = lane >> 4;
  const int r0 = blockIdx.x * 16;
  const int bidx = (r0 >> 10) & 3;

  // ---- phase 1: hyp panel (bf16) into Apan ----
  for (int q = 0; q < 32; ++q) {
    int p = tid + q * 256;                 // pair index in panel [0,8192)
    int row = p >> 9, cpi = p & 511;
    int c0 = cpi * 2;
    uint32_t i0 = (uint32_t)(r0 + row) * 1024u + (uint32_t)c0;
    float nz0, nz1;
    if (STORED) {
      uint32_t nz = *(const uint32_t*)(noiseBF + i0);
      nz0 = bf2f(nz & 0xffffu); nz1 = bf2f(nz >> 16);
    } else {
      nz0 = noise10(P, i0); nz1 = noise10(P, i0 + 1u);
    }
    uint32_t bsd = i0 & 0x3FFFFFu;
    float2 hv = *(const float2*)(hidden + bsd);
    float2 cv = *(const float2*)(cp + (bidx << 10) + c0);
    float h0 = fmaf(P.aH, hv.x, fmaf(P.aCP, cv.x, nz0));
    float h1 = fmaf(P.aH, hv.y, fmaf(P.aCP, cv.y, nz1));
    uint32_t pk = (uint32_t)bf16u(h0) | ((uint32_t)bf16u(h1) << 16);
    *(uint32_t*)(smem + APAN + pswz(row, c0 * 2)) = pk;
  }
  __syncthreads();

  // ---- phase 2: Y = Apan @ W1h^T-stage + ce -> Zpan (bf16) ----
  uint4 wreg0, wreg1, wreg2, wreg3;
  for (int g = 0; g < 4; ++g) {
    f32x4 acc[4] = {};
    {
      const uint16_t* srcb = WT1 + (size_t)(g * 256) * 1024;
      int f0 = tid, f1 = tid + 256, f2 = tid + 512, f3 = tid + 768;
      wreg0 = *(const uint4*)(srcb + (size_t)(f0 >> 2) * 1024 + (f0 & 3) * 8);
      wreg1 = *(const uint4*)(srcb + (size_t)(f1 >> 2) * 1024 + (f1 & 3) * 8);
      wreg2 = *(const uint4*)(srcb + (size_t)(f2 >> 2) * 1024 + (f2 & 3) * 8);
      wreg3 = *(const uint4*)(srcb + (size_t)(f3 >> 2) * 1024 + (f3 & 3) * 8);
    }
    for (int kt = 0; kt < 32; ++kt) {
      __syncthreads();
      {
        int f0 = tid, f1 = tid + 256, f2 = tid + 512, f3 = tid + 768;
        *(uint4*)(smem + BSOF + bswz(f0 >> 2, (f0 & 3) * 16)) = wreg0;
        *(uint4*)(smem + BSOF + bswz(f1 >> 2, (f1 & 3) * 16)) = wreg1;
        *(uint4*)(smem + BSOF + bswz(f2 >> 2, (f2 & 3) * 16)) = wreg2;
        *(uint4*)(smem + BSOF + bswz(f3 >> 2, (f3 & 3) * 16)) = wreg3;
      }
      if (kt < 31) {
        const uint16_t* srcb = WT1 + (size_t)(g * 256) * 1024 + (kt + 1) * 32;
        int f0 = tid, f1 = tid + 256, f2 = tid + 512, f3 = tid + 768;
        wreg0 = *(const uint4*)(srcb + (size_t)(f0 >> 2) * 1024 + (f0 & 3) * 8);
        wreg1 = *(const uint4*)(srcb + (size_t)(f1 >> 2) * 1024 + (f1 & 3) * 8);
        wreg2 = *(const uint4*)(srcb + (size_t)(f2 >> 2) * 1024 + (f2 & 3) * 8);
        wreg3 = *(const uint4*)(srcb + (size_t)(f3 >> 2) * 1024 + (f3 & 3) * 8);
      }
      __syncthreads();
      short8 af = *(const short8*)(smem + APAN + pswz(rl, kt * 64 + kg * 16));
      #pragma unroll
      for (int j = 0; j < 4; ++j) {
        int cl = w * 64 + j * 16 + rl;
        short8 bf = *(const short8*)(smem + BSOF + bswz(cl, kg * 16));
        acc[j] = __builtin_amdgcn_mfma_f32_16x16x32_bf16(af, bf, acc[j], 0, 0, 0);
      }
    }
    // epilogue: + ce, write Zpan bf16 (C layout: col=rl, row=kg*4+i)
    #pragma unroll
    for (int j = 0; j < 4; ++j) {
      int C = g * 256 + w * 64 + j * 16 + rl;
      float cev = ce[(bidx << 10) + C];
      #pragma unroll
      for (int i = 0; i < 4; ++i) {
        int row = kg * 4 + i;
        *(uint16_t*)(smem + ZPAN + pswz(row, C * 2)) = bf16u(acc[j][i] + cev);
      }
    }
  }
  __syncthreads();

  // ---- phase 3: LN stats (16 rows, 8 lanes/row) ----
  float* rowm = (float*)(smem + BSOF);
  float* rowr = rowm + 16;
  if (tid < 128) {
    int row = tid >> 3, l8 = tid & 7;
    float s1 = 0.f, s2 = 0.f;
    for (int j = 0; j < 128; ++j) {
      int c = l8 + j * 8;
      float v = bf2f(*(const uint16_t*)(smem + ZPAN + pswz(row, c * 2)));
      s1 += v; s2 = fmaf(v, v, s2);
    }
    #pragma unroll
    for (int o = 4; o > 0; o >>= 1) {
      s1 += __shfl_down(s1, o, 8);
      s2 += __shfl_down(s2, o, 8);
    }
    if (l8 == 0) {
      float m = s1 * (1.0f / 1024.0f);
      float var = fmaxf(s2 * (1.0f / 1024.0f) - m * m, 0.0f);
      rowm[row] = m;
      rowr[row] = 1.0f / sqrtf(var + 1e-5f);
    }
  }
  __syncthreads();

  // ---- phase 4: Z = relu(LN(Y)) in place ----
  for (int q = 0; q < 64; ++q) {
    int e = tid + q * 256;
    int row = e >> 10, col = e & 1023;
    uint16_t* zp = (uint16_t*)(smem + ZPAN + pswz(row, col * 2));
    float v = bf2f(*zp);
    float z = (v - rowm[row]) * rowr[row] * Eln_g[col] + Eln_b[col];
    *zp = bf16u(fmaxf(z, 0.f));
  }
  __syncthreads();

  // ---- phase 5: U = relu(Z @ W2 + Eb2); ep = U . Ew3 ----
  float ep0 = 0.f, ep1 = 0.f, ep2 = 0.f, ep3 = 0.f;
  for (int g = 0; g < 2; ++g) {
    f32x4 acc[4] = {};
    {
      const uint16_t* srcb = WT2 + (size_t)(g * 256) * 1024;
      int f0 = tid, f1 = tid + 256, f2 = tid + 512, f3 = tid + 768;
      wreg0 = *(const uint4*)(srcb + (size_t)(f0 >> 2) * 1024 + (f0 & 3) * 8);
      wreg1 = *(const uint4*)(srcb + (size_t)(f1 >> 2) * 1024 + (f1 & 3) * 8);
      wreg2 = *(const uint4*)(srcb + (size_t)(f2 >> 2) * 1024 + (f2 & 3) * 8);
      wreg3 = *(const uint4*)(srcb + (size_t)(f3 >> 2) * 1024 + (f3 & 3) * 8);
    }
    for (int kt = 0; kt < 32; ++kt) {
      __syncthreads();
      {
        int f0 = tid, f1 = tid + 256, f2 = tid + 512, f3 = tid + 768;
        *(uint4*)(smem + BSOF + bswz(f0 >> 2, (f0 & 3) * 16)) = wreg0;
        *(uint4*)(smem + BSOF + bswz(f1 >> 2, (f1 & 3) * 16)) = wreg1;
        *(uint4*)(smem + BSOF + bswz(f2 >> 2, (f2 & 3) * 16)) = wreg2;
        *(uint4*)(smem + BSOF + bswz(f3 >> 2, (f3 & 3) * 16)) = wreg3;
      }
      if (kt < 31) {
        const uint16_t* srcb = WT2 + (size_t)(g * 256) * 1024 + (kt + 1) * 32;
        int f0 = tid, f1 = tid + 256, f2 = tid + 512, f3 = tid + 768;
        wreg0 = *(const uint4*)(srcb + (size_t)(f0 >> 2) * 1024 + (f0 & 3) * 8);
        wreg1 = *(const uint4*)(srcb + (size_t)(f1 >> 2) * 1024 + (f1 & 3) * 8);
        wreg2 = *(const uint4*)(srcb + (size_t)(f2 >> 2) * 1024 + (f2 & 3) * 8);
        wreg3 = *(const uint4*)(srcb + (size_t)(f3 >> 2) * 1024 + (f3 & 3) * 8);
      }
      __syncthreads();
      short8 af = *(const short8*)(smem + ZPAN + pswz(rl, kt * 64 + kg * 16));
      #pragma unroll
      for (int j = 0; j < 4; ++j) {
        int cl = w * 64 + j * 16 + rl;
        short8 bf = *(const short8*)(smem + BSOF + bswz(cl, kg * 16));
        acc[j] = __builtin_amdgcn_mfma_f32_16x16x32_bf16(af, bf, acc[j], 0, 0, 0);
      }
    }
    #pragma unroll
    for (int j = 0; j < 4; ++j) {
      int C = g * 256 + w * 64 + j * 16 + rl;
      float eb = Eb2[C], w3 = Ew3[C];
      ep0 = fmaf(fmaxf(acc[j][0] + eb, 0.f), w3, ep0);
      ep1 = fmaf(fmaxf(acc[j][1] + eb, 0.f), w3, ep1);
      ep2 = fmaf(fmaxf(acc[j][2] + eb, 0.f), w3, ep2);
      ep3 = fmaf(fmaxf(acc[j][3] + eb, 0.f), w3, ep3);
    }
  }
  // reduce over the 16 lanes sharing the same rows (lane bits 0-3)
  #pragma unroll
  for (int m = 1; m < 16; m <<= 1) {
    ep0 += __shfl_xor(ep0, m);
    ep1 += __shfl_xor(ep1, m);
    ep2 += __shfl_xor(ep2, m);
    ep3 += __shfl_xor(ep3, m);
  }
  __syncthreads();
  float* red = (float*)(smem + BSOF + 256);
  if (rl == 0) {
    red[w * 16 + kg * 4 + 0] = ep0;
    red[w * 16 + kg * 4 + 1] = ep1;
    red[w * 16 + kg * 4 + 2] = ep2;
    red[w * 16 + kg * 4 + 3] = ep3;
  }
  __syncthreads();
  if (tid < 16)
    erows[r0 + tid] = red[tid] + red[16 + tid] + red[32 + tid] + red[48 + tid];
}

// energies[nb] = mean_s erows + Eb3
__global__ void k_energy(const float* __restrict__ erows, const float* __restrict__ Eb3,
                         float* __restrict__ energ) {
  __shared__ float red[256];
  int nb = blockIdx.x, tid = threadIdx.x;
  const float* x = erows + nb * 1024;
  float s = x[tid] + x[tid + 256] + x[tid + 512] + x[tid + 768];
  red[tid] = s; __syncthreads();
  for (int off = 128; off > 0; off >>= 1) { if (tid < off) red[tid] += red[tid + off]; __syncthreads(); }
  if (tid == 0) energ[nb] = red[0] * (1.0f / 1024.0f) + Eb3[0];
}

// ----------------------------- select --------------------------------------
template<bool STORED>
__global__ __launch_bounds__(256) void k_select(
    const float* __restrict__ hidden, const float* __restrict__ cp,
    const float* __restrict__ energ, const uint16_t* __restrict__ noiseBF,
    float* __restrict__ out, RngParams P)
{
  uint32_t pe = blockIdx.x * 256u + threadIdx.x;   // pair in [0, 2^21)
  uint32_t i0 = pe * 2u;
  uint32_t b = (i0 >> 20) & 3u;
  float e[8];
  #pragma unroll
  for (int n = 0; n < 8; ++n) e[n] = -energ[n * 4 + b];
  float mx = e[0];
  #pragma unroll
  for (int n = 1; n < 8; ++n) mx = fmaxf(mx, e[n]);
  float p[8]; float s = 0.f;
  #pragma unroll
  for (int n = 0; n < 8; ++n) { p[n] = expf(e[n] - mx); s += p[n]; }
  float inv = 1.0f / s;
  float2 hv = *(const float2*)(hidden + i0);
  float2 cv = *(const float2*)(cp + ((b << 10) | (i0 & 1023u)));
  float a0 = 0.f, a1 = 0.f;
  #pragma unroll
  for (int n = 0; n < 8; ++n) {
    if (STORED) {
      uint32_t nz = *(const uint32_t*)(noiseBF + ((size_t)n << 22) + i0);
      a0 = fmaf(p[n], bf2f(nz & 0xffffu), a0);
      a1 = fmaf(p[n], bf2f(nz >> 16), a1);
    } else {
      a0 = fmaf(p[n], noise10(P, i0 + ((uint32_t)n << 22)), a0);
      a1 = fmaf(p[n], noise10(P, i0 + 1u + ((uint32_t)n << 22)), a1);
    }
  }
  float o0 = fmaf(P.aH, hv.x, P.aCP * cv.x) + a0 * inv;
  float o1 = fmaf(P.aH, hv.y, P.aCP * cv.y) + a1 * inv;
  *(float2*)(out + i0) = make_float2(o0, o1);
}

// ---------------------------------------------------------------------------
extern "C" void kernel_launch(void* const* d_in, const int* in_sizes, int n_in,
                              void* d_out, int out_size, void* d_ws, size_t ws_size,
                              hipStream_t stream) {
  const float* hidden = (const float*)d_in[0];
  const float* W1    = (const float*)d_in[1];
  const float* b1    = (const float*)d_in[2];
  const float* ln1_g = (const float*)d_in[3];
  const float* ln1_b = (const float*)d_in[4];
  const float* W2    = (const float*)d_in[5];
  const float* b2    = (const float*)d_in[6];
  const float* Ew1   = (const float*)d_in[7];
  const float* Eb1   = (const float*)d_in[8];
  const float* Eln_g = (const float*)d_in[9];
  const float* Eln_b = (const float*)d_in[10];
  const float* Ew2   = (const float*)d_in[11];
  const float* Eb2   = (const float*)d_in[12];
  const float* Ew3   = (const float*)d_in[13];
  const float* Eb3   = (const float*)d_in[14];
  float* out = (float*)d_out;

  // ws carve
  const size_t NOISE_B = (size_t)NELEM * 2;            // 64 MiB
  const size_t WT1_B   = 1024ull * 1024 * 2;           // 2 MiB
  const size_t WT2_B   = 512ull * 1024 * 2;            // 1 MiB
  const size_t SMALL_B = (4096 + 8192 + 4096 + 4096 + 32768 + 32) * 4;
  bool big = ws_size >= NOISE_B + WT1_B + WT2_B + SMALL_B + 1024;

  char* ws = (char*)d_ws;
  uint16_t* noiseBF = nullptr;
  size_t off = 0;
  if (big) { noiseBF = (uint16_t*)ws; off += NOISE_B; }
  uint16_t* WT1 = (uint16_t*)(ws + off); off += WT1_B;
  uint16_t* WT2 = (uint16_t*)(ws + off); off += WT2_B;
  float* ctx   = (float*)(ws + off);
  float* t1    = ctx + 4096;
  float* cp    = t1 + 8192;
  float* ce    = cp + 4096;
  float* erows = ce + 4096;
  float* energ = erows + 32768;

  // host-side RNG params
  RngParams P;
  for (uint32_t t = 0; t < 10; ++t) {
    uint32_t o0, o1;
    tf2x32(0u, 42u, 0u, t, o0, o1);
    P.k0[t] = o0; P.k1[t] = o1;
  }
  double a = pow(0.99, 10);
  P.coef[0] = (float)(0.1 * a);
  for (int j = 1; j <= 9; ++j) P.coef[j] = (float)(0.01 * pow(0.99, 10 - j));
  P.aH = (float)a;
  P.aCP = (float)(1.0 - a);

  k_wcvt<<<dim3(16, 16), 256, 0, stream>>>(Ew1, WT1, 1024, 1024);  // W1h^T bf16
  k_wcvt<<<dim3(8, 16), 256, 0, stream>>>(Ew2, WT2, 1024, 512);    // W2^T bf16
  k_ctx<<<16, 256, 0, stream>>>(hidden, ctx);
  k_fc1<<<32, 256, 0, stream>>>(ctx, W1, b1, t1);
  k_ln_relu<<<4, 256, 0, stream>>>(t1, ln1_g, ln1_b);
  k_fc2<<<dim3(16, 2), 256, 0, stream>>>(t1, W2, b2, ctx, Ew1 + (size_t)1024 * 1024, Eb1, cp, ce);
  if (big) {
    k_noise<<<65536, 256, 0, stream>>>((uint32_t*)noiseBF, P);
    k_fused<true><<<2048, 256, 0, stream>>>(hidden, cp, ce, noiseBF, WT1, WT2,
                                            Eln_g, Eln_b, Eb2, Ew3, erows, P);
  } else {
    k_fused<false><<<2048, 256, 0, stream>>>(hidden, cp, ce, nullptr, WT1, WT2,
                                             Eln_g, Eln_b, Eb2, Ew3, erows, P);
  }
  k_energy<<<32, 256, 0, stream>>>(erows, Eb3, energ);
  if (big)
    k_select<true><<<8192, 256, 0, stream>>>(hidden, cp, energ, noiseBF, out, P);
  else
    k_select<false><<<8192, 256, 0, stream>>>(hidden, cp, energ, nullptr, out, P);
}

// Round 5
// 1165.922 us; speedup vs baseline: 6.6353x; 1.1321x over previous
//
#include <hip/hip_runtime.h>
#include <hip/hip_bf16.h>
#include <stdint.h>
#include <math.h>

// ---------------------------------------------------------------------------
// PCN Exploration layer. B=4, S=1024, D=1024, NS=8, NT=10.
// hyp = a*(hidden + 0.1*expl) + (1-a)*cp + sum_j c_j*noise_j  (a=0.99^10)
// Round 5: identical to round 4 except the k_select<BIG> low-half decode fix
// (bf2f(pk<<16) double-shifted -> always 0; now __uint_as_float(pk<<16)).
// ---------------------------------------------------------------------------

#define NS_ 8
#define B_ 4
#define S_ 1024
#define D_ 1024
#define NROWS (NS_*B_*S_)            // 32768
#define NELEM (1u<<25)

typedef __attribute__((ext_vector_type(8))) short short8;
typedef __attribute__((ext_vector_type(4))) float f32x4;

struct RngParams {
  uint32_t k0[10], k1[10];
  float coef[10];
  float aH, aCP;
};

// ----------------------------- threefry -----------------------------------
__host__ __device__ __forceinline__ uint32_t rotl32_(uint32_t x, int r) {
  return (x << r) | (x >> (32 - r));
}

__host__ __device__ __forceinline__ void tf2x32(uint32_t k0, uint32_t k1,
                                                uint32_t x0, uint32_t x1,
                                                uint32_t &o0, uint32_t &o1) {
  uint32_t k2 = k0 ^ k1 ^ 0x1BD11BDAu;
  x0 += k0; x1 += k1;
  x0 += x1; x1 = rotl32_(x1, 13); x1 ^= x0;
  x0 += x1; x1 = rotl32_(x1, 15); x1 ^= x0;
  x0 += x1; x1 = rotl32_(x1, 26); x1 ^= x0;
  x0 += x1; x1 = rotl32_(x1, 6);  x1 ^= x0;
  x0 += k1; x1 += k2 + 1u;
  x0 += x1; x1 = rotl32_(x1, 17); x1 ^= x0;
  x0 += x1; x1 = rotl32_(x1, 29); x1 ^= x0;
  x0 += x1; x1 = rotl32_(x1, 16); x1 ^= x0;
  x0 += x1; x1 = rotl32_(x1, 24); x1 ^= x0;
  x0 += k2; x1 += k0 + 2u;
  x0 += x1; x1 = rotl32_(x1, 13); x1 ^= x0;
  x0 += x1; x1 = rotl32_(x1, 15); x1 ^= x0;
  x0 += x1; x1 = rotl32_(x1, 26); x1 ^= x0;
  x0 += x1; x1 = rotl32_(x1, 6);  x1 ^= x0;
  x0 += k0; x1 += k1 + 3u;
  x0 += x1; x1 = rotl32_(x1, 17); x1 ^= x0;
  x0 += x1; x1 = rotl32_(x1, 29); x1 ^= x0;
  x0 += x1; x1 = rotl32_(x1, 16); x1 ^= x0;
  x0 += x1; x1 = rotl32_(x1, 24); x1 ^= x0;
  x0 += k1; x1 += k2 + 4u;
  x0 += x1; x1 = rotl32_(x1, 13); x1 ^= x0;
  x0 += x1; x1 = rotl32_(x1, 15); x1 ^= x0;
  x0 += x1; x1 = rotl32_(x1, 26); x1 ^= x0;
  x0 += x1; x1 = rotl32_(x1, 6);  x1 ^= x0;
  x0 += k2; x1 += k0 + 5u;
  o0 = x0; o1 = x1;
}

// bits -> N(0,1): XLA ErfInv32 poly; fast -log(1-x^2) via (1-x)(1+x)
__device__ __forceinline__ float bits_to_normal(uint32_t bits) {
  const float lo = -0.99999994f;
  float f = __uint_as_float((bits >> 9) | 0x3f800000u) - 1.0f;
  float x = fmaxf(lo, f * 2.0f + lo);
  float t = (1.0f - x) * (1.0f + x);
  float w = -__logf(t);
  float p;
  if (w < 5.0f) {
    w = w - 2.5f;
    p = 2.81022636e-08f;
    p = fmaf(p, w, 3.43273939e-07f);
    p = fmaf(p, w, -3.5233877e-06f);
    p = fmaf(p, w, -4.39150654e-06f);
    p = fmaf(p, w, 0.00021858087f);
    p = fmaf(p, w, -0.00125372503f);
    p = fmaf(p, w, -0.00417768164f);
    p = fmaf(p, w, 0.246640727f);
    p = fmaf(p, w, 1.50140941f);
  } else {
    w = sqrtf(w) - 3.0f;
    p = -0.000200214257f;
    p = fmaf(p, w, 0.000100950558f);
    p = fmaf(p, w, 0.00134934322f);
    p = fmaf(p, w, -0.00367342844f);
    p = fmaf(p, w, 0.00573950773f);
    p = fmaf(p, w, -0.0076224613f);
    p = fmaf(p, w, 0.00943887047f);
    p = fmaf(p, w, 1.00167406f);
    p = fmaf(p, w, 2.83297682f);
  }
  return 1.41421356f * (p * x);
}

__device__ __forceinline__ float noise10(const RngParams& P, uint32_t i) {
  float acc = 0.f;
  #pragma unroll
  for (int j = 0; j < 10; ++j) {
    uint32_t w0, w1;
    tf2x32(P.k0[j], P.k1[j], 0u, i, w0, w1);
    acc = fmaf(P.coef[j], bits_to_normal(w0 ^ w1), acc);
  }
  return acc;
}

__device__ __forceinline__ uint16_t bf16u(float x) {
  __hip_bfloat16 h = __float2bfloat16(x);
  return *(uint16_t*)&h;
}
__device__ __forceinline__ float bf2f(uint32_t u) {
  return __uint_as_float(u << 16);
}

// ----------------------------- small kernels -------------------------------
// ctx two-stage: A) 256 blocks x 16 s-rows -> part[256][1024]; B) reduce.
__global__ void k_ctxA(const float* __restrict__ hidden, float* __restrict__ part) {
  int b = blockIdx.x >> 6, ch = blockIdx.x & 63;
  const float* p = hidden + (size_t)b * (S_ * D_) + (size_t)ch * 16 * 1024;
  int tid = threadIdx.x;
  #pragma unroll
  for (int k = 0; k < 4; ++k) {
    int d = tid + k * 256;
    float s = 0.f;
    #pragma unroll
    for (int t = 0; t < 16; ++t) s += p[t * 1024 + d];
    part[(size_t)blockIdx.x * 1024 + d] = s;
  }
}
__global__ void k_ctxB(const float* __restrict__ part, float* __restrict__ ctx) {
  int idx = blockIdx.x * 256 + threadIdx.x;   // 0..4095
  int b = idx >> 10, d = idx & 1023;
  float s = 0.f;
  #pragma unroll 8
  for (int c = 0; c < 64; ++c) s += part[((size_t)(b * 64 + c)) * 1024 + d];
  ctx[idx] = s * (1.0f / 1024.0f);
}

// t1[b][j] = ctx[b].W1[:,j] + b1[j]; 128 blocks: 4 waves x 64 outputs, K-split 4
__global__ void k_fc1(const float* __restrict__ ctx, const float* __restrict__ W1,
                      const float* __restrict__ b1, float* __restrict__ t1) {
  __shared__ float red[4][64];
  int b = blockIdx.x >> 5;                   // 4 batches
  int j0 = (blockIdx.x & 31) * 64;           // 32 blocks/batch
  int l = threadIdx.x & 63, w = threadIdx.x >> 6;
  int j = j0 + l;
  const float* c = ctx + b * 1024 + w * 256;
  const float* wp = W1 + (size_t)(w * 256) * 2048 + j;
  float s = 0.f;
  #pragma unroll 8
  for (int k = 0; k < 256; ++k) s += c[k] * wp[(size_t)k * 2048];
  red[w][l] = s; __syncthreads();
  if (w == 0)
    t1[b * 2048 + j] = red[0][l] + red[1][l] + red[2][l] + red[3][l] + b1[j];
}

__global__ void k_ln_relu(float* __restrict__ t1, const float* __restrict__ g,
                          const float* __restrict__ bb) {
  __shared__ float red[256];
  int row = blockIdx.x, tid = threadIdx.x;
  float* x = t1 + row * 2048;
  float v[8];
  #pragma unroll
  for (int q = 0; q < 8; ++q) v[q] = x[tid + q * 256];
  float s = 0.f;
  #pragma unroll
  for (int q = 0; q < 8; ++q) s += v[q];
  red[tid] = s; __syncthreads();
  for (int off = 128; off > 0; off >>= 1) { if (tid < off) red[tid] += red[tid + off]; __syncthreads(); }
  float m = red[0] * (1.0f / 2048.0f);
  __syncthreads();
  float s2 = 0.f;
  #pragma unroll
  for (int q = 0; q < 8; ++q) { float d = v[q] - m; s2 += d * d; }
  red[tid] = s2; __syncthreads();
  for (int off = 128; off > 0; off >>= 1) { if (tid < off) red[tid] += red[tid + off]; __syncthreads(); }
  float var = red[0] * (1.0f / 2048.0f);
  float rs = 1.0f / sqrtf(var + 1e-5f);
  #pragma unroll
  for (int q = 0; q < 8; ++q) {
    int j = tid + q * 256;
    float z = (v[q] - m) * rs * g[j] + bb[j];
    x[j] = fmaxf(z, 0.0f);
  }
}

// y=0: cp = t1n.W2 + b2 (K=2048); y=1: ce = ctx.Ew1c + Eb1 (K=1024). 64x2 blocks.
__global__ void k_fc2(const float* __restrict__ t1, const float* __restrict__ W2,
                      const float* __restrict__ b2, const float* __restrict__ ctx,
                      const float* __restrict__ Ew1c, const float* __restrict__ Eb1,
                      float* __restrict__ cp, float* __restrict__ ce) {
  __shared__ float red[4][64];
  int b = blockIdx.x >> 4;                   // 4 batches
  int j0 = (blockIdx.x & 15) * 64;           // 16 blocks/batch
  int l = threadIdx.x & 63, w = threadIdx.x >> 6;
  int j = j0 + l;
  float s = 0.f;
  if (blockIdx.y == 0) {
    const float* a = t1 + b * 2048 + w * 512;
    const float* wp = W2 + (size_t)(w * 512) * 1024 + j;
    #pragma unroll 8
    for (int k = 0; k < 512; ++k) s += a[k] * wp[(size_t)k * 1024];
  } else {
    const float* a = ctx + b * 1024 + w * 256;
    const float* wp = Ew1c + (size_t)(w * 256) * 1024 + j;
    #pragma unroll 8
    for (int k = 0; k < 256; ++k) s += a[k] * wp[(size_t)k * 1024];
  }
  red[w][l] = s; __syncthreads();
  if (w == 0) {
    float r = red[0][l] + red[1][l] + red[2][l] + red[3][l];
    if (blockIdx.y == 0) cp[b * 1024 + j] = r + b2[j];
    else                 ce[b * 1024 + j] = r + Eb1[j];
  }
}

// --------------- weight transpose + f32->bf16:  dst[N][K] = src[K][N] ------
__global__ void k_wcvt(const float* __restrict__ src, uint16_t* __restrict__ dst,
                       int K, int N) {
  __shared__ float tile[64][65];
  int n0 = blockIdx.x * 64, k0 = blockIdx.y * 64;
  int tid = threadIdx.x;
  #pragma unroll
  for (int i = 0; i < 16; ++i) {
    int lin = tid + i * 256;
    int tr = lin >> 6, tc = lin & 63;
    tile[tr][tc] = src[(size_t)(k0 + tr) * N + n0 + tc];
  }
  __syncthreads();
  #pragma unroll
  for (int i = 0; i < 8; ++i) {
    int lin = tid + i * 256;
    int tr = lin >> 5, tc2 = (lin & 31) * 2;
    uint32_t pk = (uint32_t)bf16u(tile[tc2][tr]) | ((uint32_t)bf16u(tile[tc2 + 1][tr]) << 16);
    *(uint32_t*)(&dst[(size_t)(n0 + tr) * K + k0 + tc2]) = pk;
  }
}

// ----------------------------- fused energy (MFMA) -------------------------
// 2048 blocks x 256 thr; block = 16 rows. LDS: Apan 32K | Zpan 32K | Bs 16K.
#define APAN 0
#define ZPAN 32768
#define BSOF 65536

__device__ __forceinline__ int pswz(int row, int byteInRow) {   // panel swizzle
  return (row * 2048 + byteInRow) ^ ((row & 7) << 4);
}
__device__ __forceinline__ int bswz(int c, int kbyte) {         // B-stage swizzle
  return (c * 64 + kbyte) ^ ((c & 7) << 4);
}

template<bool BIG>
__global__ __launch_bounds__(256, 2) void k_fused(
    const float* __restrict__ hidden, const float* __restrict__ cp,
    const float* __restrict__ ce, uint32_t* __restrict__ hypPairs,
    const uint16_t* __restrict__ WT1, const uint16_t* __restrict__ WT2,
    const float* __restrict__ Eln_g, const float* __restrict__ Eln_b,
    const float* __restrict__ Eb2, const float* __restrict__ Ew3,
    float* __restrict__ erows, RngParams P)
{
  __shared__ __align__(16) char smem[81920];
  const int tid = threadIdx.x;
  const int lane = tid & 63;
  const int w = tid >> 6;
  const int rl = lane & 15;
  const int kg = lane >> 4;
  const int r0 = blockIdx.x * 16;
  const int bidx = (r0 >> 10) & 3;

  // ---- phase 1: threefry noise + hyp panel (bf16) -> Apan (+ global store) --
  for (int q = 0; q < 32; ++q) {
    int p = tid + q * 256;                 // pair index in panel [0,8192)
    int row = p >> 9, cpi = p & 511;
    int c0 = cpi * 2;
    uint32_t i0 = (uint32_t)(r0 + row) * 1024u + (uint32_t)c0;
    float nz0 = noise10(P, i0);
    float nz1 = noise10(P, i0 + 1u);
    uint32_t bsd = i0 & 0x3FFFFFu;
    float2 hv = *(const float2*)(hidden + bsd);
    float2 cv = *(const float2*)(cp + (bidx << 10) + c0);
    float h0 = fmaf(P.aH, hv.x, fmaf(P.aCP, cv.x, nz0));
    float h1 = fmaf(P.aH, hv.y, fmaf(P.aCP, cv.y, nz1));
    uint32_t pk = (uint32_t)bf16u(h0) | ((uint32_t)bf16u(h1) << 16);
    *(uint32_t*)(smem + APAN + pswz(row, c0 * 2)) = pk;
    if (BIG) hypPairs[i0 >> 1] = pk;       // coalesced 4B/lane stream write
  }
  __syncthreads();

  // ---- phase 2: Y = Apan @ WT1-stage + ce -> Zpan (bf16) ----
  uint4 wreg0, wreg1, wreg2, wreg3;
  for (int g = 0; g < 4; ++g) {
    f32x4 acc[4] = {};
    {
      const uint16_t* srcb = WT1 + (size_t)(g * 256) * 1024;
      int f0 = tid, f1 = tid + 256, f2 = tid + 512, f3 = tid + 768;
      wreg0 = *(const uint4*)(srcb + (size_t)(f0 >> 2) * 1024 + (f0 & 3) * 8);
      wreg1 = *(const uint4*)(srcb + (size_t)(f1 >> 2) * 1024 + (f1 & 3) * 8);
      wreg2 = *(const uint4*)(srcb + (size_t)(f2 >> 2) * 1024 + (f2 & 3) * 8);
      wreg3 = *(const uint4*)(srcb + (size_t)(f3 >> 2) * 1024 + (f3 & 3) * 8);
    }
    for (int kt = 0; kt < 32; ++kt) {
      __syncthreads();
      {
        int f0 = tid, f1 = tid + 256, f2 = tid + 512, f3 = tid + 768;
        *(uint4*)(smem + BSOF + bswz(f0 >> 2, (f0 & 3) * 16)) = wreg0;
        *(uint4*)(smem + BSOF + bswz(f1 >> 2, (f1 & 3) * 16)) = wreg1;
        *(uint4*)(smem + BSOF + bswz(f2 >> 2, (f2 & 3) * 16)) = wreg2;
        *(uint4*)(smem + BSOF + bswz(f3 >> 2, (f3 & 3) * 16)) = wreg3;
      }
      if (kt < 31) {
        const uint16_t* srcb = WT1 + (size_t)(g * 256) * 1024 + (kt + 1) * 32;
        int f0 = tid, f1 = tid + 256, f2 = tid + 512, f3 = tid + 768;
        wreg0 = *(const uint4*)(srcb + (size_t)(f0 >> 2) * 1024 + (f0 & 3) * 8);
        wreg1 = *(const uint4*)(srcb + (size_t)(f1 >> 2) * 1024 + (f1 & 3) * 8);
        wreg2 = *(const uint4*)(srcb + (size_t)(f2 >> 2) * 1024 + (f2 & 3) * 8);
        wreg3 = *(const uint4*)(srcb + (size_t)(f3 >> 2) * 1024 + (f3 & 3) * 8);
      }
      __syncthreads();
      short8 af = *(const short8*)(smem + APAN + pswz(rl, kt * 64 + kg * 16));
      #pragma unroll
      for (int j = 0; j < 4; ++j) {
        int cl = w * 64 + j * 16 + rl;
        short8 bf = *(const short8*)(smem + BSOF + bswz(cl, kg * 16));
        acc[j] = __builtin_amdgcn_mfma_f32_16x16x32_bf16(af, bf, acc[j], 0, 0, 0);
      }
    }
    #pragma unroll
    for (int j = 0; j < 4; ++j) {
      int C = g * 256 + w * 64 + j * 16 + rl;
      float cev = ce[(bidx << 10) + C];
      #pragma unroll
      for (int i = 0; i < 4; ++i) {
        int row = kg * 4 + i;
        *(uint16_t*)(smem + ZPAN + pswz(row, C * 2)) = bf16u(acc[j][i] + cev);
      }
    }
  }
  __syncthreads();

  // ---- phase 3: LN stats ----
  float* rowm = (float*)(smem + BSOF);
  float* rowr = rowm + 16;
  if (tid < 128) {
    int row = tid >> 3, l8 = tid & 7;
    float s1 = 0.f, s2 = 0.f;
    for (int j = 0; j < 128; ++j) {
      int c = l8 + j * 8;
      float v = bf2f(*(const uint16_t*)(smem + ZPAN + pswz(row, c * 2)));
      s1 += v; s2 = fmaf(v, v, s2);
    }
    #pragma unroll
    for (int o = 4; o > 0; o >>= 1) {
      s1 += __shfl_down(s1, o, 8);
      s2 += __shfl_down(s2, o, 8);
    }
    if (l8 == 0) {
      float m = s1 * (1.0f / 1024.0f);
      float var = fmaxf(s2 * (1.0f / 1024.0f) - m * m, 0.0f);
      rowm[row] = m;
      rowr[row] = 1.0f / sqrtf(var + 1e-5f);
    }
  }
  __syncthreads();

  // ---- phase 4: Z = relu(LN(Y)) in place ----
  for (int q = 0; q < 64; ++q) {
    int e = tid + q * 256;
    int row = e >> 10, col = e & 1023;
    uint16_t* zp = (uint16_t*)(smem + ZPAN + pswz(row, col * 2));
    float v = bf2f(*zp);
    float z = (v - rowm[row]) * rowr[row] * Eln_g[col] + Eln_b[col];
    *zp = bf16u(fmaxf(z, 0.f));
  }
  __syncthreads();

  // ---- phase 5: U = relu(Z @ WT2 + Eb2); ep = U . Ew3 ----
  float ep0 = 0.f, ep1 = 0.f, ep2 = 0.f, ep3 = 0.f;
  for (int g = 0; g < 2; ++g) {
    f32x4 acc[4] = {};
    {
      const uint16_t* srcb = WT2 + (size_t)(g * 256) * 1024;
      int f0 = tid, f1 = tid + 256, f2 = tid + 512, f3 = tid + 768;
      wreg0 = *(const uint4*)(srcb + (size_t)(f0 >> 2) * 1024 + (f0 & 3) * 8);
      wreg1 = *(const uint4*)(srcb + (size_t)(f1 >> 2) * 1024 + (f1 & 3) * 8);
      wreg2 = *(const uint4*)(srcb + (size_t)(f2 >> 2) * 1024 + (f2 & 3) * 8);
      wreg3 = *(const uint4*)(srcb + (size_t)(f3 >> 2) * 1024 + (f3 & 3) * 8);
    }
    for (int kt = 0; kt < 32; ++kt) {
      __syncthreads();
      {
        int f0 = tid, f1 = tid + 256, f2 = tid + 512, f3 = tid + 768;
        *(uint4*)(smem + BSOF + bswz(f0 >> 2, (f0 & 3) * 16)) = wreg0;
        *(uint4*)(smem + BSOF + bswz(f1 >> 2, (f1 & 3) * 16)) = wreg1;
        *(uint4*)(smem + BSOF + bswz(f2 >> 2, (f2 & 3) * 16)) = wreg2;
        *(uint4*)(smem + BSOF + bswz(f3 >> 2, (f3 & 3) * 16)) = wreg3;
      }
      if (kt < 31) {
        const uint16_t* srcb = WT2 + (size_t)(g * 256) * 1024 + (kt + 1) * 32;
        int f0 = tid, f1 = tid + 256, f2 = tid + 512, f3 = tid + 768;
        wreg0 = *(const uint4*)(srcb + (size_t)(f0 >> 2) * 1024 + (f0 & 3) * 8);
        wreg1 = *(const uint4*)(srcb + (size_t)(f1 >> 2) * 1024 + (f1 & 3) * 8);
        wreg2 = *(const uint4*)(srcb + (size_t)(f2 >> 2) * 1024 + (f2 & 3) * 8);
        wreg3 = *(const uint4*)(srcb + (size_t)(f3 >> 2) * 1024 + (f3 & 3) * 8);
      }
      __syncthreads();
      short8 af = *(const short8*)(smem + ZPAN + pswz(rl, kt * 64 + kg * 16));
      #pragma unroll
      for (int j = 0; j < 4; ++j) {
        int cl = w * 64 + j * 16 + rl;
        short8 bf = *(const short8*)(smem + BSOF + bswz(cl, kg * 16));
        acc[j] = __builtin_amdgcn_mfma_f32_16x16x32_bf16(af, bf, acc[j], 0, 0, 0);
      }
    }
    #pragma unroll
    for (int j = 0; j < 4; ++j) {
      int C = g * 256 + w * 64 + j * 16 + rl;
      float eb = Eb2[C], w3 = Ew3[C];
      ep0 = fmaf(fmaxf(acc[j][0] + eb, 0.f), w3, ep0);
      ep1 = fmaf(fmaxf(acc[j][1] + eb, 0.f), w3, ep1);
      ep2 = fmaf(fmaxf(acc[j][2] + eb, 0.f), w3, ep2);
      ep3 = fmaf(fmaxf(acc[j][3] + eb, 0.f), w3, ep3);
    }
  }
  #pragma unroll
  for (int m = 1; m < 16; m <<= 1) {
    ep0 += __shfl_xor(ep0, m);
    ep1 += __shfl_xor(ep1, m);
    ep2 += __shfl_xor(ep2, m);
    ep3 += __shfl_xor(ep3, m);
  }
  __syncthreads();
  float* red = (float*)(smem + BSOF + 256);
  if (rl == 0) {
    red[w * 16 + kg * 4 + 0] = ep0;
    red[w * 16 + kg * 4 + 1] = ep1;
    red[w * 16 + kg * 4 + 2] = ep2;
    red[w * 16 + kg * 4 + 3] = ep3;
  }
  __syncthreads();
  if (tid < 16)
    erows[r0 + tid] = red[tid] + red[16 + tid] + red[32 + tid] + red[48 + tid];
}

// energies[nb] = mean_s erows + Eb3
__global__ void k_energy(const float* __restrict__ erows, const float* __restrict__ Eb3,
                         float* __restrict__ energ) {
  __shared__ float red[256];
  int nb = blockIdx.x, tid = threadIdx.x;
  const float* x = erows + nb * 1024;
  float s = x[tid] + x[tid + 256] + x[tid + 512] + x[tid + 768];
  red[tid] = s; __syncthreads();
  for (int off = 128; off > 0; off >>= 1) { if (tid < off) red[tid] += red[tid + off]; __syncthreads(); }
  if (tid == 0) energ[nb] = red[0] * (1.0f / 1024.0f) + Eb3[0];
}

// ----------------------------- select --------------------------------------
template<bool BIG>
__global__ __launch_bounds__(256) void k_select(
    const float* __restrict__ hidden, const float* __restrict__ cp,
    const float* __restrict__ energ, const uint32_t* __restrict__ hypPairs,
    float* __restrict__ out, RngParams P)
{
  uint32_t pe = blockIdx.x * 256u + threadIdx.x;   // pair in [0, 2^21)
  uint32_t i0 = pe * 2u;
  uint32_t b = (i0 >> 20) & 3u;
  float e[8];
  #pragma unroll
  for (int n = 0; n < 8; ++n) e[n] = -energ[n * 4 + b];
  float mx = e[0];
  #pragma unroll
  for (int n = 1; n < 8; ++n) mx = fmaxf(mx, e[n]);
  float p[8]; float s = 0.f;
  #pragma unroll
  for (int n = 0; n < 8; ++n) { p[n] = expf(e[n] - mx); s += p[n]; }
  float inv = 1.0f / s;
  float a0 = 0.f, a1 = 0.f;
  if (BIG) {
    #pragma unroll
    for (int n = 0; n < 8; ++n) {
      uint32_t pk = hypPairs[pe + ((uint32_t)n << 21)];
      a0 = fmaf(p[n], __uint_as_float(pk << 16), a0);           // low bf16
      a1 = fmaf(p[n], __uint_as_float(pk & 0xffff0000u), a1);   // high bf16
    }
    *(float2*)(out + i0) = make_float2(a0 * inv, a1 * inv);
  } else {
    float2 hv = *(const float2*)(hidden + i0);
    float2 cv = *(const float2*)(cp + ((b << 10) | (i0 & 1023u)));
    #pragma unroll
    for (int n = 0; n < 8; ++n) {
      a0 = fmaf(p[n], noise10(P, i0 + ((uint32_t)n << 22)), a0);
      a1 = fmaf(p[n], noise10(P, i0 + 1u + ((uint32_t)n << 22)), a1);
    }
    float o0 = fmaf(P.aH, hv.x, P.aCP * cv.x) + a0 * inv;
    float o1 = fmaf(P.aH, hv.y, P.aCP * cv.y) + a1 * inv;
    *(float2*)(out + i0) = make_float2(o0, o1);
  }
}

// ---------------------------------------------------------------------------
extern "C" void kernel_launch(void* const* d_in, const int* in_sizes, int n_in,
                              void* d_out, int out_size, void* d_ws, size_t ws_size,
                              hipStream_t stream) {
  const float* hidden = (const float*)d_in[0];
  const float* W1    = (const float*)d_in[1];
  const float* b1    = (const float*)d_in[2];
  const float* ln1_g = (const float*)d_in[3];
  const float* ln1_b = (const float*)d_in[4];
  const float* W2    = (const float*)d_in[5];
  const float* b2    = (const float*)d_in[6];
  const float* Ew1   = (const float*)d_in[7];
  const float* Eb1   = (const float*)d_in[8];
  const float* Eln_g = (const float*)d_in[9];
  const float* Eln_b = (const float*)d_in[10];
  const float* Ew2   = (const float*)d_in[11];
  const float* Eb2   = (const float*)d_in[12];
  const float* Ew3   = (const float*)d_in[13];
  const float* Eb3   = (const float*)d_in[14];
  float* out = (float*)d_out;

  // ws carve: hyp-bf16 64 MiB + WT1 2 MiB + WT2 1 MiB + part 1 MiB + smalls
  const size_t HYP_B  = (size_t)NELEM * 2;           // 64 MiB (bf16 pairs)
  const size_t WT1_B  = 1024ull * 1024 * 2;          // 2 MiB
  const size_t WT2_B  = 512ull * 1024 * 2;           // 1 MiB
  const size_t PART_B = 256ull * 1024 * 4;           // 1 MiB
  const size_t SMALL_B = (4096 + 8192 + 4096 + 4096 + 32768 + 32) * 4;
  bool big = ws_size >= HYP_B + WT1_B + WT2_B + PART_B + SMALL_B + 1024;

  char* ws = (char*)d_ws;
  uint32_t* hypPairs = nullptr;
  size_t off = 0;
  if (big) { hypPairs = (uint32_t*)ws; off += HYP_B; }
  uint16_t* WT1 = (uint16_t*)(ws + off); off += WT1_B;
  uint16_t* WT2 = (uint16_t*)(ws + off); off += WT2_B;
  float* part  = (float*)(ws + off);     off += PART_B;
  float* ctx   = (float*)(ws + off);
  float* t1    = ctx + 4096;
  float* cp    = t1 + 8192;
  float* ce    = cp + 4096;
  float* erows = ce + 4096;
  float* energ = erows + 32768;

  // host-side RNG params
  RngParams P;
  for (uint32_t t = 0; t < 10; ++t) {
    uint32_t o0, o1;
    tf2x32(0u, 42u, 0u, t, o0, o1);
    P.k0[t] = o0; P.k1[t] = o1;
  }
  double a = pow(0.99, 10);
  P.coef[0] = (float)(0.1 * a);
  for (int j = 1; j <= 9; ++j) P.coef[j] = (float)(0.01 * pow(0.99, 10 - j));
  P.aH = (float)a;
  P.aCP = (float)(1.0 - a);

  k_wcvt<<<dim3(16, 16), 256, 0, stream>>>(Ew1, WT1, 1024, 1024);  // Ew1_h^T bf16
  k_wcvt<<<dim3(8, 16), 256, 0, stream>>>(Ew2, WT2, 1024, 512);    // Ew2^T bf16
  k_ctxA<<<256, 256, 0, stream>>>(hidden, part);
  k_ctxB<<<16, 256, 0, stream>>>(part, ctx);
  k_fc1<<<128, 256, 0, stream>>>(ctx, W1, b1, t1);
  k_ln_relu<<<4, 256, 0, stream>>>(t1, ln1_g, ln1_b);
  k_fc2<<<dim3(64, 2), 256, 0, stream>>>(t1, W2, b2, ctx, Ew1 + (size_t)1024 * 1024, Eb1, cp, ce);
  if (big)
    k_fused<true><<<2048, 256, 0, stream>>>(hidden, cp, ce, hypPairs, WT1, WT2,
                                            Eln_g, Eln_b, Eb2, Ew3, erows, P);
  else
    k_fused<false><<<2048, 256, 0, stream>>>(hidden, cp, ce, nullptr, WT1, WT2,
                                             Eln_g, Eln_b, Eb2, Ew3, erows, P);
  k_energy<<<32, 256, 0, stream>>>(erows, Eb3, energ);
  if (big)
    k_select<true><<<8192, 256, 0, stream>>>(hidden, cp, energ, hypPairs, out, P);
  else
    k_select<false><<<8192, 256, 0, stream>>>(hidden, cp, energ, nullptr, out, P);
}